// Round 7
// baseline (17690.091 us; speedup 1.0000x reference)
//
#include <hip/hip_runtime.h>

// LSTM_88776974008866: bidirectional LSTM (B=2048, S=128, H=512, in=4) + 4 sigmoid heads.
// Round 7: SYNC-FREE decomposition. Each block owns 16 batch rows x ALL 2048 gate-cols
// for one direction; h and c never leave the block (h in LDS, c in VGPRs), W streams
// from L2 every step (2.18 MB/CU/step). No atomics, no flags, no cooperative launch,
// no cross-block coherence — one intra-block __syncthreads per step. x*Wih+bias is a
// 17th K-slice of the GEMM. LDS sized 84KB to force exactly 1 block/CU.

typedef __attribute__((ext_vector_type(8))) __bf16 bf16x8;
typedef __attribute__((ext_vector_type(4))) float f32x4;
typedef __attribute__((ext_vector_type(8))) unsigned short u16x8;

__device__ __forceinline__ unsigned short f2bf(float f) {
  unsigned u = __float_as_uint(f);
  u += 0x7fffu + ((u >> 16) & 1u);   // round-to-nearest-even
  return (unsigned short)(u >> 16);
}
__device__ __forceinline__ float bf2f(unsigned short s) {
  return __uint_as_float(((unsigned)s) << 16);
}
__device__ __forceinline__ float sigm(float x) { return 1.0f / (1.0f + __expf(-x)); }
__device__ __forceinline__ float tanhfast(float x) {
  float e = __expf(-2.0f * fabsf(x));
  float t = (1.0f - e) / (1.0f + e);
  return x < 0.0f ? -t : t;
}

// ---------------------------------------------------------------------------
// prep: build per-dir fragment-contiguous W image, 17 K-slices (16 real + tail).
// chunk flat = ((dir*17 + kt)*128 + F)*64 + lane, 16B each.
//   lane: l15 = B-col n = F*16+l15 (permuted: gate=F&3, j=(F>>2)*16+l15),
//         lhi = k-quad; kt<16: k = kt*32 + lhi*8 + e of Whh[orig][k].
//   kt==16 (tail): lhi==0 -> {wih[orig][0..3], bias_ih+bias_hh, 0,0,0}; else 0.
// ---------------------------------------------------------------------------
__global__ __launch_bounds__(256) void prep_k(
    const float* __restrict__ Wf_hh, const float* __restrict__ Wf_ih,
    const float* __restrict__ bf_ih, const float* __restrict__ bf_hh,
    const float* __restrict__ Wb_hh, const float* __restrict__ Wb_ih,
    const float* __restrict__ bb_ih, const float* __restrict__ bb_hh,
    unsigned short* __restrict__ Wimg)
{
  int flat = blockIdx.x * 256 + threadIdx.x;   // 0 .. 278527
  int lane = flat & 63;
  int F = (flat >> 6) & 127;
  int dk = flat >> 13;                         // 0..33
  int dir = (dk >= 17) ? 1 : 0;
  int kt = dk - 17 * dir;
  int l15 = lane & 15, lhi = lane >> 4;
  const float* Whh = dir ? Wb_hh : Wf_hh;
  const float* Wih = dir ? Wb_ih : Wf_ih;
  const float* bih = dir ? bb_ih : bf_ih;
  const float* bhh = dir ? bb_hh : bf_hh;

  int gate = F & 3;
  int j = ((F >> 2) << 4) + l15;
  int orig = (gate << 9) + j;                  // gate-major row in [0,2048)

  u16x8 o = {};
  if (kt < 16) {
    int k0 = (kt << 5) + (lhi << 3);
    const float4* src = (const float4*)(Whh + (size_t)orig * 512 + k0);
    float4 a = src[0], b = src[1];
    o[0] = f2bf(a.x); o[1] = f2bf(a.y); o[2] = f2bf(a.z); o[3] = f2bf(a.w);
    o[4] = f2bf(b.x); o[5] = f2bf(b.y); o[6] = f2bf(b.z); o[7] = f2bf(b.w);
  } else if (lhi == 0) {
    o[0] = f2bf(Wih[orig * 4 + 0]);
    o[1] = f2bf(Wih[orig * 4 + 1]);
    o[2] = f2bf(Wih[orig * 4 + 2]);
    o[3] = f2bf(Wih[orig * 4 + 3]);
    o[4] = f2bf(bih[orig] + bhh[orig]);
  }
  *(u16x8*)(Wimg + (size_t)flat * 8) = o;
}

// ---------------------------------------------------------------------------
// Sync-free LSTM: 256 blocks x 512 threads, 1 block/CU (LDS-forced).
// Block: dir = bid&1, batch rows [ (bid>>1)*16, +16 ). Per step:
// GEMM [16 x 544] x [544 x 2048] via 17 K-slices (A from LDS, B streamed from
// L2, x/bias as slice 16), lane-local cell update, h -> LDS (next step's A).
// h LDS layout == A-fragment layout: byte(row,k) = (k>>5)*1024 + ((k>>3)&3)*256
// + row*16 + (k&7)*2, so A-reads are contiguous 1KB ds_read_b128 per slice.
// ---------------------------------------------------------------------------
__global__ __launch_bounds__(512, 2) void lstm_stream(
    const float* __restrict__ y,
    const unsigned short* __restrict__ Wimg,
    unsigned short* __restrict__ hf, unsigned short* __restrict__ hb)
{
  __shared__ alignas(16) unsigned char smem[86016];   // >80KB => 1 block/CU
  const int tid = threadIdx.x;
  const int w = tid >> 6, lane = tid & 63;
  const int l15 = lane & 15, lhi = lane >> 4;
  const int bid = blockIdx.x;
  const int dir = bid & 1;
  const int r0 = (bid >> 1) << 4;              // first batch row of this block

  unsigned char* hbuf0 = smem;                 // 17408 B each (17 x 1KB slices)
  unsigned char* hbuf1 = smem + 17408;

  // zero both h buffers (h(t=-1)=0; tail zeros for lhi>0 stay forever)
  for (int i = tid; i < 8704; i += 512) ((unsigned*)smem)[i] = 0u;

  const float4* y4 = (const float4*)y;
  if (tid < 16) {                              // x(t=0) into hbuf0 tail slice
    float4 x4 = y4[(size_t)(r0 + tid) * 128 + (dir ? 127 : 0)];
    u16x8 xc = {};
    xc[0] = f2bf(x4.x); xc[1] = f2bf(x4.y); xc[2] = f2bf(x4.z); xc[3] = f2bf(x4.w);
    xc[4] = 0x3F80;                            // 1.0 -> picks up bias row
    *(u16x8*)(hbuf0 + 16384 + tid * 16) = xc;
  }

  float c_reg[16];
#pragma unroll
  for (int i = 0; i < 16; ++i) c_reg[i] = 0.f;

  // this wave's W stream base: dir image + wave's 16-frag band
  const unsigned char* WB = (const unsigned char*)Wimg
      + ((size_t)dir * (17u << 17)) + ((size_t)w << 14);
  unsigned short* hog = dir ? hb : hf;

  __syncthreads();

#pragma unroll 1
  for (int t = 0; t < 128; ++t) {
    const unsigned char* hc = (t & 1) ? hbuf1 : hbuf0;
    unsigned char* hn = (t & 1) ? hbuf0 : hbuf1;

    f32x4 acc[16];
#pragma unroll
    for (int i = 0; i < 16; ++i) acc[i] = (f32x4){0.f, 0.f, 0.f, 0.f};

    bf16x8 Aa[2], Bb[3][8];
    Aa[0] = *(const bf16x8*)(hc + (lane << 4));
#pragma unroll
    for (int q = 0; q < 8; ++q)
      Bb[0][q] = *(const bf16x8*)(WB + (q << 10) + (lane << 4));
#pragma unroll
    for (int q = 0; q < 8; ++q)
      Bb[1][q] = *(const bf16x8*)(WB + ((8 + q) << 10) + (lane << 4));

    // 34 half-slices (kt, half), 3-buffer rotation, prefetch distance 2.
    // All indices compile-time after unroll (rule #20).
#pragma unroll
    for (int g = 0; g < 34; ++g) {
      const int kt = g >> 1, fb = (g & 1) << 3;
      if (g + 2 < 34) {
        const int g2 = g + 2;
        const int kt2 = g2 >> 1, fb2 = (g2 & 1) << 3;
        if (fb2 == 0)
          Aa[kt2 & 1] = *(const bf16x8*)(hc + (kt2 << 10) + (lane << 4));
#pragma unroll
        for (int q = 0; q < 8; ++q)
          Bb[g2 % 3][q] = *(const bf16x8*)(WB + ((size_t)kt2 << 17)
                                              + ((size_t)(fb2 + q) << 10) + (lane << 4));
      }
#pragma unroll
      for (int q = 0; q < 8; ++q)
        acc[fb + q] = __builtin_amdgcn_mfma_f32_16x16x32_bf16(
            Aa[kt & 1], Bb[g % 3][q], acc[fb + q], 0, 0, 0);
    }

    // ---- epilogue: lane-local cell update; h -> LDS (or global at t=127) ----
    const bool last = (t == 127);
#pragma unroll
    for (int g4 = 0; g4 < 4; ++g4) {
      const int j = (((w << 2) + g4) << 4) + l15;          // hidden index 0..511
#pragma unroll
      for (int r = 0; r < 4; ++r) {
        const float ig = sigm(acc[(g4 << 2) + 0][r]);
        const float fg = sigm(acc[(g4 << 2) + 1][r]);
        const float gg = tanhfast(acc[(g4 << 2) + 2][r]);
        const float og = sigm(acc[(g4 << 2) + 3][r]);
        const float cn = fg * c_reg[(g4 << 2) + r] + ig * gg;
        c_reg[(g4 << 2) + r] = cn;
        const unsigned short hv = f2bf(og * tanhfast(cn));
        const int row = (lhi << 2) + r;
        if (last) {
          hog[(size_t)(r0 + row) * 512 + j] = hv;
        } else {
          const int boff = ((j >> 5) << 10) | (((j >> 3) & 3) << 8)
                         | (row << 4) | ((j & 7) << 1);
          *(unsigned short*)(hn + boff) = hv;
        }
      }
    }

    if (!last) {
      if (tid < 16) {                          // x(t+1) into next tail slice
        const int tn = t + 1;
        float4 x4 = y4[(size_t)(r0 + tid) * 128 + (dir ? 127 - tn : tn)];
        u16x8 xc = {};
        xc[0] = f2bf(x4.x); xc[1] = f2bf(x4.y); xc[2] = f2bf(x4.z); xc[3] = f2bf(x4.w);
        xc[4] = 0x3F80;
        *(u16x8*)(hn + 16384 + tid * 16) = xc;
      }
      __syncthreads();                         // intra-block only — cheap
    }
  }
}

// ---------------------------------------------------------------------------
// heads: out[b][k] = sigmoid(hf[b]·Wk[0:512] + hb[b]·Wk[512:1024] + bk)
// ---------------------------------------------------------------------------
__global__ __launch_bounds__(256) void heads_k(
    const unsigned short* __restrict__ hf, const unsigned short* __restrict__ hb,
    const float* __restrict__ W1, const float* __restrict__ b1,
    const float* __restrict__ W2, const float* __restrict__ b2,
    const float* __restrict__ W3, const float* __restrict__ b3,
    const float* __restrict__ W4, const float* __restrict__ b4,
    float* __restrict__ out)
{
  const int wid = threadIdx.x >> 6, lane = threadIdx.x & 63;
  const int b = blockIdx.x * 4 + wid;
  const unsigned short* src = (lane < 32) ? (hf + ((size_t)b << 9) + (lane << 4))
                                          : (hb + ((size_t)b << 9) + ((lane - 32) << 4));
  const int woff = lane << 4;
  u16x8 v0 = *(const u16x8*)src;
  u16x8 v1 = *(const u16x8*)(src + 8);
  float hv[16];
#pragma unroll
  for (int e = 0; e < 8; ++e) { hv[e] = bf2f(v0[e]); hv[8 + e] = bf2f(v1[e]); }
  float s0 = 0.f, s1 = 0.f, s2 = 0.f, s3 = 0.f;
#pragma unroll
  for (int e = 0; e < 16; ++e) {
    float h = hv[e];
    s0 += h * W1[woff + e];
    s1 += h * W2[woff + e];
    s2 += h * W3[woff + e];
    s3 += h * W4[woff + e];
  }
#pragma unroll
  for (int off = 32; off >= 1; off >>= 1) {
    s0 += __shfl_xor(s0, off, 64);
    s1 += __shfl_xor(s1, off, 64);
    s2 += __shfl_xor(s2, off, 64);
    s3 += __shfl_xor(s3, off, 64);
  }
  if (lane == 0) {
    out[b * 4 + 0] = sigm(s0 + b1[0]);
    out[b * 4 + 1] = sigm(s1 + b2[0]);
    out[b * 4 + 2] = sigm(s2 + b3[0]);
    out[b * 4 + 3] = sigm(s3 + b4[0]);
  }
}

// ---------------------------------------------------------------------------
extern "C" void kernel_launch(void* const* d_in, const int* in_sizes, int n_in,
                              void* d_out, int out_size, void* d_ws, size_t ws_size,
                              hipStream_t stream) {
  (void)in_sizes; (void)n_in; (void)out_size; (void)ws_size;
  const float* y     = (const float*)d_in[0];
  const float* Wf_ih = (const float*)d_in[1];
  const float* Wf_hh = (const float*)d_in[2];
  const float* bf_ih = (const float*)d_in[3];
  const float* bf_hh = (const float*)d_in[4];
  const float* Wb_ih = (const float*)d_in[5];
  const float* Wb_hh = (const float*)d_in[6];
  const float* bb_ih = (const float*)d_in[7];
  const float* bb_hh = (const float*)d_in[8];
  const float* W1 = (const float*)d_in[9];  const float* b1 = (const float*)d_in[10];
  const float* W2 = (const float*)d_in[11]; const float* b2 = (const float*)d_in[12];
  const float* W3 = (const float*)d_in[13]; const float* b3 = (const float*)d_in[14];
  const float* W4 = (const float*)d_in[15]; const float* b4 = (const float*)d_in[16];

  char* ws = (char*)d_ws;
  const size_t MB = 1ull << 20;
  unsigned short* Wimg = (unsigned short*)(ws);           // 4.25 MB W images
  unsigned short* hf   = (unsigned short*)(ws + 6 * MB);  // 2 MB final fwd h
  unsigned short* hb   = (unsigned short*)(ws + 8 * MB);  // 2 MB final bwd h

  prep_k<<<1088, 256, 0, stream>>>(Wf_hh, Wf_ih, bf_ih, bf_hh,
                                   Wb_hh, Wb_ih, bb_ih, bb_hh, Wimg);

  lstm_stream<<<256, 512, 0, stream>>>(y, Wimg, hf, hb);

  heads_k<<<512, 256, 0, stream>>>(hf, hb, W1, b1, W2, b2, W3, b3, W4, b4,
                                   (float*)d_out);
}

// Round 8
// 2495.500 us; speedup vs baseline: 7.0888x; 7.0888x over previous
//
#include <hip/hip_runtime.h>

// LSTM_88776974008866: bidirectional LSTM (B=2048, S=128, H=512, in=4) + 4 sigmoid heads.
// Round 8: persistent cooperative kernel with XCD-EXACT groups and L2-only coherence.
//  - Groups discovered at runtime from HW_REG_XCC_ID + per-XCD rank counter (no bid->XCD
//    heuristic; r7 disproved bid%8/bid&1 assumptions).
//  - NO agent acquire/release anywhere in the hot loop (r3: acquire=invl2 => 25GB LLC
//    refetch, 22us/step; r4/r5: release=wbl2 => 525MB HBM writes). All flag ops are
//    RELAXED atomics (RMW executes at the coherence point, no cache maintenance).
//  - h exchange: plain stores into the XCD-shared L2 + per-step L1-only invalidate
//    (`buffer_inv sc0`), publish = vmcnt(0) + LDS arrival + relaxed fetch_add.
//  - W stationary in LDS (fragment-contiguous, conflict-free ds_read_b128);
//    x*Wih+bias folded into a tail MFMA; c in registers; depth-3/2 prefetch ring.

typedef __attribute__((ext_vector_type(8))) __bf16 bf16x8;
typedef __attribute__((ext_vector_type(4))) float f32x4;
typedef __attribute__((ext_vector_type(8))) unsigned short u16x8;

__device__ __forceinline__ unsigned short f2bf(float f) {
  unsigned u = __float_as_uint(f);
  u += 0x7fffu + ((u >> 16) & 1u);   // round-to-nearest-even
  return (unsigned short)(u >> 16);
}
__device__ __forceinline__ float bf2f(unsigned short s) {
  return __uint_as_float(((unsigned)s) << 16);
}
__device__ __forceinline__ float sigm(float x) { return 1.0f / (1.0f + __expf(-x)); }
__device__ __forceinline__ float tanhfast(float x) {
  float e = __expf(-2.0f * fabsf(x));
  float t = (1.0f - e) / (1.0f + e);
  return x < 0.0f ? -t : t;
}

__device__ __forceinline__ void gl_lds16(const void* g, void* l) {
  __builtin_amdgcn_global_load_lds(
      (const __attribute__((address_space(1))) unsigned int*)g,
      (__attribute__((address_space(3))) unsigned int*)l, 16, 0, 0);
}

// ---------------------------------------------------------------------------
// prep: Whh (fp32 [2048][512], gate-major rows i,f,g,o) -> Wp fragment image:
//   chunk = ((((dir*16+ni)*2+wn)*16+kt)*4+nf)*64 + lhi*16 + l15   (16B chunks)
// Also wtail[dir][permrow][8] = {wih[0..3], bias, 0,0,0} bf16 for the tail MFMA.
// ---------------------------------------------------------------------------
__global__ __launch_bounds__(256) void prep_k(
    const float* __restrict__ Wf_hh, const float* __restrict__ Wf_ih,
    const float* __restrict__ bf_ih, const float* __restrict__ bf_hh,
    const float* __restrict__ Wb_hh, const float* __restrict__ Wb_ih,
    const float* __restrict__ bb_ih, const float* __restrict__ bb_hh,
    unsigned short* __restrict__ Wp, unsigned short* __restrict__ wtailp)
{
  int flat = blockIdx.x * 256 + threadIdx.x;   // 0 .. 262143
  int l15 = flat & 15;
  int lhi = (flat >> 4) & 3;
  int nf  = (flat >> 6) & 3;
  int kt  = (flat >> 8) & 15;
  int wn  = (flat >> 12) & 1;
  int ni  = (flat >> 13) & 15;
  int dir = (flat >> 17) & 1;
  const float* Whh = dir ? Wb_hh : Wf_hh;
  const float* Wih = dir ? Wb_ih : Wf_ih;
  const float* bih = dir ? bb_ih : bf_ih;
  const float* bhh = dir ? bb_hh : bf_hh;

  int j = ((ni * 2 + wn) << 4) + l15;          // hidden index 0..511
  int orig = (nf << 9) + j;                    // original gate-major row
  int k0 = (kt << 5) + (lhi << 3);
  const float4* src = (const float4*)(Whh + (size_t)orig * 512 + k0);
  float4 a = src[0], b = src[1];
  u16x8 o;
  o[0] = f2bf(a.x); o[1] = f2bf(a.y); o[2] = f2bf(a.z); o[3] = f2bf(a.w);
  o[4] = f2bf(b.x); o[5] = f2bf(b.y); o[6] = f2bf(b.z); o[7] = f2bf(b.w);
  *(u16x8*)(Wp + (size_t)flat * 8) = o;

  if (kt == 0 && lhi == 0) {
    int rg = (ni << 7) + (wn << 6) + (nf << 4) + l15;   // permuted row
    unsigned short* wt = wtailp + (((size_t)(dir << 11) + rg) << 3);
    wt[0] = f2bf(Wih[orig * 4 + 0]);
    wt[1] = f2bf(Wih[orig * 4 + 1]);
    wt[2] = f2bf(Wih[orig * 4 + 2]);
    wt[3] = f2bf(Wih[orig * 4 + 3]);
    wt[4] = f2bf(bih[orig] + bhh[orig]);
    wt[5] = 0; wt[6] = 0; wt[7] = 0;
  }
}

__device__ __forceinline__ void mfma16(const bf16x8 av[4], const bf16x8 bv[4],
                                       f32x4 acc[4][4]) {
#pragma unroll
  for (int mf = 0; mf < 4; ++mf)
#pragma unroll
    for (int nf = 0; nf < 4; ++nf)
      acc[mf][nf] = __builtin_amdgcn_mfma_f32_16x16x32_bf16(av[mf], bv[nf], acc[mf][nf], 0, 0, 0);
}

// ---------------------------------------------------------------------------
// Persistent kernel: 256 blocks x 512 threads (1 block/CU via 128KB LDS),
// cooperative launch => all co-resident => exactly 32 blocks per XCD.
// Runtime role assignment: xcc = HW_REG_XCC_ID; rank = per-XCD counter;
// dir = rank>>4, ni = rank&15, mi = xcc. The 16 blocks of (xcc,dir) produce
// and consume one h panel -- all sharing one physical L2 BY CONSTRUCTION.
// ctrl layout (uints): [xcc<<5]          : per-XCD rank counters (128B apart)
//                      [256 + grp<<5]    : per-(xcc,dir) step flags
// ---------------------------------------------------------------------------
__global__ __launch_bounds__(512, 2) void lstm_persist(
    const float* __restrict__ y,
    const unsigned short* __restrict__ Wp,
    const unsigned short* __restrict__ wtailp,
    unsigned short* __restrict__ hf0, unsigned short* __restrict__ hf1,
    unsigned short* __restrict__ hb0, unsigned short* __restrict__ hb1,
    unsigned* __restrict__ ctrl)
{
  __shared__ alignas(16) unsigned short Wl[65536];   // 128 KB W image
  __shared__ unsigned arrive_cnt;
  __shared__ unsigned rank_sh;

  const int tid = threadIdx.x;
  const int w = tid >> 6, lane = tid & 63;

  unsigned xcc;
  asm("s_getreg_b32 %0, hwreg(HW_REG_XCC_ID)" : "=s"(xcc));
  xcc &= 7u;

  if (tid == 0) {
    arrive_cnt = 0u;
    rank_sh = __hip_atomic_fetch_add(ctrl + (xcc << 5), 1u,
                                     __ATOMIC_RELAXED, __HIP_MEMORY_SCOPE_AGENT);
  }
  __syncthreads();
  const int rank = (int)(rank_sh & 31u);
  const int dir = rank >> 4;               // 16 fwd + 16 bwd blocks per XCD
  const int ni  = rank & 15;
  const int mi  = (int)xcc;
  const int bm0 = mi << 8;                 // this XCD's 256 batch rows

  unsigned short* h0 = dir ? hb0 : hf0;
  unsigned short* h1 = dir ? hb1 : hf1;

  const int wm = w >> 1;                   // 0..3: 64-row quarter
  const int wn = w & 1;                    // 0..1: 64-col half
  const int l15 = lane & 15;
  const int lhi = lane >> 4;

  // ---- one-time: copy this block's 128KB W image into LDS (contiguous) ----
  const unsigned short* Wblk = Wp + ((size_t)((dir << 4) | ni) << 16);
#pragma unroll
  for (int i = 0; i < 16; ++i) {
    gl_lds16(Wblk + (size_t)(((i << 9) + tid)) * 8,
             (unsigned short*)Wl + ((i << 12) + (w << 9)));
  }

  // ---- tail B-fragments (wih + bias), register-resident ----
  bf16x8 btail[4];
#pragma unroll
  for (int nf = 0; nf < 4; ++nf) {
    u16x8 wt = *(const u16x8*)(wtailp +
        (((size_t)(dir << 11) + ((ni << 7) | (wn << 6) | (nf << 4) | l15))) * 8);
    u16x8 z = {};
    u16x8 sel = (lhi == 0) ? wt : z;
    btail[nf] = *(bf16x8*)&sel;
  }

  const int j = (((ni << 1) + wn) << 4) + l15;   // hidden index 0..511
  float c_reg[16];
#pragma unroll
  for (int i = 0; i < 16; ++i) c_reg[i] = 0.f;

  const float4* y4 = (const float4*)y;
  unsigned* gflag = ctrl + 256 + ((((unsigned)mi << 1) | (unsigned)dir) << 5);

  // LDS B-fragment base for this wave (contiguous 1KB per (kt,nf) read)
  const unsigned short* wB = Wl + (wn << 15) + (lane << 3);

  __syncthreads();   // Wl ready (drains global_load_lds)

  const unsigned short* hin = h0;
  unsigned short* hout = h1;

#pragma unroll 1
  for (int t = 0; t < 128; ++t) {
    const int t_eff = dir ? (127 - t) : t;

    // ---- x loads (independent of the flag) ----
    float4 xr[4];
#pragma unroll
    for (int mf = 0; mf < 4; ++mf)
      xr[mf] = y4[(size_t)(bm0 + (wm << 6) + (mf << 4) + l15) * 128 + t_eff];

    // ---- wait for group peers (relaxed RMW-of-0 poll: executes at the atomic
    //      point, always fresh, NO cache maintenance), then L1-only invalidate ----
    if (t) {
      if (w == 0) {
        const unsigned tgt = (unsigned)(t << 4);   // 16*t cumulative publishes
        unsigned v = 0;
        while (true) {
          if (lane == 0)
            v = __hip_atomic_fetch_add(gflag, 0u, __ATOMIC_RELAXED,
                                       __HIP_MEMORY_SCOPE_AGENT);
          v = (unsigned)__builtin_amdgcn_readfirstlane((int)v);
          if (v >= tgt) break;
          __builtin_amdgcn_s_sleep(2);
        }
      }
      __syncthreads();
      asm volatile("buffer_inv sc0\n\ts_waitcnt vmcnt(0)" ::: "memory");
    }

    f32x4 acc[4][4];
#pragma unroll
    for (int a = 0; a < 4; ++a)
#pragma unroll
      for (int b = 0; b < 4; ++b) acc[a][b] = (f32x4){0.f, 0.f, 0.f, 0.f};

    if (t) {
      const unsigned short* aBase =
          hin + ((size_t)(bm0 + (wm << 6) + l15) << 9) + (lhi << 3);

      bf16x8 aA[3][4], bT[2][4];

#define ALOAD(kk, sl)                                                          \
      do {                                                                     \
        const unsigned short* ap_ = aBase + ((kk) << 5);                       \
        aA[sl][0] = *(const bf16x8*)(ap_);                                     \
        aA[sl][1] = *(const bf16x8*)(ap_ + (16 << 9));                         \
        aA[sl][2] = *(const bf16x8*)(ap_ + (32 << 9));                         \
        aA[sl][3] = *(const bf16x8*)(ap_ + (48 << 9));                         \
      } while (0)
#define BLOAD(kk, sl)                                                          \
      do {                                                                     \
        const unsigned short* bp_ = wB + ((kk) << 11);                         \
        bT[sl][0] = *(const bf16x8*)(bp_);                                     \
        bT[sl][1] = *(const bf16x8*)(bp_ + 512);                               \
        bT[sl][2] = *(const bf16x8*)(bp_ + 1024);                              \
        bT[sl][3] = *(const bf16x8*)(bp_ + 1536);                              \
      } while (0)

      // prologue: A slices 0..2, B slices 0..1
      ALOAD(0, 0); ALOAD(1, 1); ALOAD(2, 2);
      BLOAD(0, 0); BLOAD(1, 1);

      // tail MFMA while prologue loads are in flight
      {
        bf16x8 atail[4];
#pragma unroll
        for (int mf = 0; mf < 4; ++mf) {
          u16x8 at = {};
          if (lhi == 0) {
            at[0] = f2bf(xr[mf].x); at[1] = f2bf(xr[mf].y);
            at[2] = f2bf(xr[mf].z); at[3] = f2bf(xr[mf].w);
            at[4] = 0x3F80;   // 1.0 -> picks up bias row
          }
          atail[mf] = *(bf16x8*)&at;
        }
        mfma16(atail, btail, acc);
      }

#pragma unroll
      for (int i = 0; i < 16; ++i) {
        __builtin_amdgcn_s_setprio(1);
        mfma16(aA[i % 3], bT[i & 1], acc);
        __builtin_amdgcn_s_setprio(0);
        if (i < 13) ALOAD(i + 3, (i + 3) % 3);
        if (i < 14) BLOAD(i + 2, i & 1);
      }
#undef ALOAD
#undef BLOAD
    } else {
      // t=0: h=0, GEMM skipped; just tail
      bf16x8 atail[4];
#pragma unroll
      for (int mf = 0; mf < 4; ++mf) {
        u16x8 at = {};
        if (lhi == 0) {
          at[0] = f2bf(xr[mf].x); at[1] = f2bf(xr[mf].y);
          at[2] = f2bf(xr[mf].z); at[3] = f2bf(xr[mf].w);
          at[4] = 0x3F80;
        }
        atail[mf] = *(bf16x8*)&at;
      }
      mfma16(atail, btail, acc);
    }

    // ---- epilogue: lane-local LSTM cell update, c in registers ----
#pragma unroll
    for (int mf = 0; mf < 4; ++mf) {
#pragma unroll
      for (int r = 0; r < 4; ++r) {
        const float ig = sigm(acc[mf][0][r]);
        const float fg = sigm(acc[mf][1][r]);
        const float gg = tanhfast(acc[mf][2][r]);
        const float og = sigm(acc[mf][3][r]);
        const float cn = fg * c_reg[mf * 4 + r] + ig * gg;
        c_reg[mf * 4 + r] = cn;
        const int b = bm0 + (wm << 6) + (mf << 4) + (lhi << 2) + r;
        hout[((size_t)b << 9) + j] = f2bf(og * tanhfast(cn));
      }
    }

    // ---- publish: per-wave store drain -> LDS arrival -> 8th wave relaxed RMW ----
    if (t != 127) {
      asm volatile("s_waitcnt vmcnt(0)" ::: "memory");   // own h stores in L2
      if (lane == 0) {
        unsigned old = atomicAdd(&arrive_cnt, 1u);       // intra-block LDS atomic
        if (old == (unsigned)((t << 3) + 7)) {           // last of 8 waves this step
          __hip_atomic_fetch_add(gflag, 1u, __ATOMIC_RELAXED,
                                 __HIP_MEMORY_SCOPE_AGENT);
        }
      }
    }

    const unsigned short* tmp = hin; hin = hout; hout = (unsigned short*)tmp;
  }
}

// ---------------------------------------------------------------------------
// heads: out[b][k] = sigmoid(hf[b]·Wk[0:512] + hb[b]·Wk[512:1024] + bk)
// ---------------------------------------------------------------------------
__global__ __launch_bounds__(256) void heads_k(
    const unsigned short* __restrict__ hf, const unsigned short* __restrict__ hb,
    const float* __restrict__ W1, const float* __restrict__ b1,
    const float* __restrict__ W2, const float* __restrict__ b2,
    const float* __restrict__ W3, const float* __restrict__ b3,
    const float* __restrict__ W4, const float* __restrict__ b4,
    float* __restrict__ out)
{
  const int wid = threadIdx.x >> 6, lane = threadIdx.x & 63;
  const int b = blockIdx.x * 4 + wid;
  const unsigned short* src = (lane < 32) ? (hf + ((size_t)b << 9) + (lane << 4))
                                          : (hb + ((size_t)b << 9) + ((lane - 32) << 4));
  const int woff = lane << 4;
  u16x8 v0 = *(const u16x8*)src;
  u16x8 v1 = *(const u16x8*)(src + 8);
  float hv[16];
#pragma unroll
  for (int e = 0; e < 8; ++e) { hv[e] = bf2f(v0[e]); hv[8 + e] = bf2f(v1[e]); }
  float s0 = 0.f, s1 = 0.f, s2 = 0.f, s3 = 0.f;
#pragma unroll
  for (int e = 0; e < 16; ++e) {
    float h = hv[e];
    s0 += h * W1[woff + e];
    s1 += h * W2[woff + e];
    s2 += h * W3[woff + e];
    s3 += h * W4[woff + e];
  }
#pragma unroll
  for (int off = 32; off >= 1; off >>= 1) {
    s0 += __shfl_xor(s0, off, 64);
    s1 += __shfl_xor(s1, off, 64);
    s2 += __shfl_xor(s2, off, 64);
    s3 += __shfl_xor(s3, off, 64);
  }
  if (lane == 0) {
    out[b * 4 + 0] = sigm(s0 + b1[0]);
    out[b * 4 + 1] = sigm(s1 + b2[0]);
    out[b * 4 + 2] = sigm(s2 + b3[0]);
    out[b * 4 + 3] = sigm(s3 + b4[0]);
  }
}

// ---------------------------------------------------------------------------
extern "C" void kernel_launch(void* const* d_in, const int* in_sizes, int n_in,
                              void* d_out, int out_size, void* d_ws, size_t ws_size,
                              hipStream_t stream) {
  (void)in_sizes; (void)n_in; (void)out_size; (void)ws_size;
  const float* y     = (const float*)d_in[0];
  const float* Wf_ih = (const float*)d_in[1];
  const float* Wf_hh = (const float*)d_in[2];
  const float* bf_ih = (const float*)d_in[3];
  const float* bf_hh = (const float*)d_in[4];
  const float* Wb_ih = (const float*)d_in[5];
  const float* Wb_hh = (const float*)d_in[6];
  const float* bb_ih = (const float*)d_in[7];
  const float* bb_hh = (const float*)d_in[8];
  const float* W1 = (const float*)d_in[9];  const float* b1 = (const float*)d_in[10];
  const float* W2 = (const float*)d_in[11]; const float* b2 = (const float*)d_in[12];
  const float* W3 = (const float*)d_in[13]; const float* b3 = (const float*)d_in[14];
  const float* W4 = (const float*)d_in[15]; const float* b4 = (const float*)d_in[16];

  char* ws = (char*)d_ws;
  const size_t MB = 1ull << 20;
  unsigned short* Wp    = (unsigned short*)(ws);            // 4MB: per-(dir,ni) LDS images
  unsigned short* hf0   = (unsigned short*)(ws + 4 * MB);   // 2MB
  unsigned short* hb0   = (unsigned short*)(ws + 6 * MB);   // 2MB
  unsigned short* hf1   = (unsigned short*)(ws + 8 * MB);   // 2MB
  unsigned short* hb1   = (unsigned short*)(ws + 10 * MB);  // 2MB
  unsigned short* wtail = (unsigned short*)(ws + 12 * MB);  // 64KB
  unsigned* ctrl        = (unsigned*)(ws + 13 * MB);        // rank counters + flags

  hipMemsetAsync(ws + 4 * MB, 0, 4 * MB, stream);    // hf0+hb0 = h(t=0) zeros
  hipMemsetAsync(ws + 13 * MB, 0, 8192, stream);     // ctrl: counters + flags

  prep_k<<<1024, 256, 0, stream>>>(Wf_hh, Wf_ih, bf_ih, bf_hh,
                                   Wb_hh, Wb_ih, bb_ih, bb_hh,
                                   Wp, wtail);

  void* args[] = { (void*)&y, (void*)&Wp, (void*)&wtail,
                   (void*)&hf0, (void*)&hf1, (void*)&hb0, (void*)&hb1, (void*)&ctrl };
  hipLaunchCooperativeKernel((const void*)lstm_persist, dim3(256), dim3(512),
                             args, 0, stream);

  // 128 steps (even): final h is in buffer 0 for both directions
  heads_k<<<512, 256, 0, stream>>>(hf0, hb0, W1, b1, W2, b2, W3, b3, W4, b4,
                                   (float*)d_out);
}